// Round 17
// baseline (279.207 us; speedup 1.0000x reference)
//
#include <hip/hip_runtime.h>

// ---------------------------------------------------------------------------
// Attention_msa: B=1, N=2048, C=1024, H=8, d=128, SCALE=25, SIM_THRESH=0.75
// ---------------------------------------------------------------------------

#define NTOK 2048
#define CDIM 1024

typedef __attribute__((ext_vector_type(8))) short bf16x8;
typedef __attribute__((ext_vector_type(4))) short s16x4;
typedef __attribute__((ext_vector_type(2))) short s16x2;
typedef __attribute__((ext_vector_type(4))) float f32x4;

#define MFMA16(a,b,c) __builtin_amdgcn_mfma_f32_16x16x32_bf16((a),(b),(c),0,0,0)

__device__ __forceinline__ short f2bf(float x){
  unsigned u = __float_as_uint(x);
  u += 0x7FFFu + ((u >> 16) & 1u);           // round-to-nearest-even
  return (short)(u >> 16);
}

__device__ __forceinline__ float bf2f(short s){
  return __uint_as_float(((unsigned)(unsigned short)s) << 16);
}

__device__ __forceinline__ int cvtpk(float lo, float hi){
  int r;
  asm("v_cvt_pk_bf16_f32 %0, %1, %2" : "=v"(r) : "v"(lo), "v"(hi));
  return r;
}

__device__ __forceinline__ void atomAddF(float* p, float v){
  unsafeAtomicAdd(p, v);                     // global_atomic_add_f32
}

// async global->LDS, 16B per lane; LDS dest = uniform base + lane*16
__device__ __forceinline__ void gld16(const short* g, short* l){
  __builtin_amdgcn_global_load_lds(
      (const __attribute__((address_space(1))) unsigned int*)g,
      (__attribute__((address_space(3))) unsigned int*)l, 16, 0, 0);
}

// ---------------------------------------------------------------------------
// Kernel 0: f32 -> bf16 conversion of GEMM inputs (one pass).
// ---------------------------------------------------------------------------
__global__ __launch_bounds__(256,8) void k_cvt(
    const float* __restrict__ xc, const float* __restrict__ xr,
    const float* __restrict__ Wc, const float* __restrict__ Wr,
    short* __restrict__ xbc, short* __restrict__ xbr,
    short* __restrict__ wbc, short* __restrict__ wbr)
{
  int idx = blockIdx.x*256 + threadIdx.x;    // 0..1179647
  const float* src; short* dst; int off;
  if      (idx <  262144){ src = xc; dst = xbc; off = idx; }
  else if (idx <  524288){ src = xr; dst = xbr; off = idx - 262144; }
  else if (idx <  917504){ src = Wc; dst = wbc; off = idx - 524288; }
  else                   { src = Wr; dst = wbr; off = idx - 917504; }
  float4 a = *(const float4*)(src + (size_t)off*8);
  float4 b = *(const float4*)(src + (size_t)off*8 + 4);
  bf16x8 o = { f2bf(a.x), f2bf(a.y), f2bf(a.z), f2bf(a.w),
               f2bf(b.x), f2bf(b.y), f2bf(b.z), f2bf(b.w) };
  *(bf16x8*)(dst + (size_t)off*8) = o;
}

// ---------------------------------------------------------------------------
// Kernel 1: QKV GEMM + FUSED per-head L2 norm (unchanged).
// ---------------------------------------------------------------------------
__global__ __launch_bounds__(256,3) void k_qkv(
    const short* __restrict__ xbc, const short* __restrict__ xbr,
    const short* __restrict__ wbc, const short* __restrict__ wbr,
    short* __restrict__ qc, short* __restrict__ kc,
    short* __restrict__ qr, short* __restrict__ kr,
    short* __restrict__ vn, short* __restrict__ vb,
    float* __restrict__ out)
{
  const int tid = threadIdx.x;
  const int l   = tid & 63;
  const int w   = tid >> 6;
  const int fr  = l & 15;
  const int g   = l >> 4;
  const int fk8 = g * 8;

  const int L     = blockIdx.x;
  const int xcd   = L & 7;
  const int slot  = L >> 3;              // 0..79
  const int panel = xcd*5 + (slot >> 4); // 0..39
  const int mb    = slot & 15;
  const int m0    = mb * 128;
  const int o0    = panel * 128;

  const short* Xb; const short* Wb; int wrow;
  if (o0 < 3072){ Xb = xbc; Wb = wbc; wrow = o0; }
  else          { Xb = xbr; Wb = wbr; wrow = o0 - 3072; }

  __shared__ __align__(16) short Ab[2][8][64][8];   // 16KB (double)
  __shared__ __align__(16) short Bb[2][8][64][8];   // 16KB (double)
  __shared__ float nbuf[128][2];

  const int wr = w >> 1;
  const int wc = w & 1;

#define QSTAGE(DB, KN) do {                                                  \
    _Pragma("unroll")                                                        \
    for (int it=0; it<2; ++it){                                              \
      int f = it*4 + w;                                                      \
      gld16(Xb + (size_t)(m0  + f*16 + fr)*CDIM + (KN) + fk8,                \
            &Ab[DB][f][0][0]);                                               \
      gld16(Wb + (size_t)(wrow + f*16 + fr)*CDIM + (KN) + fk8,               \
            &Bb[DB][f][0][0]);                                               \
    }                                                                        \
  } while(0)

  f32x4 acc[4][4] = {};

  QSTAGE(0, 0);
  __syncthreads();

  for (int kt = 0; kt < 32; ++kt){
    const int db = kt & 1;
    if (kt < 31){ if (db) QSTAGE(0, (kt+1)*32); else QSTAGE(1, (kt+1)*32); }
    bf16x8 af[4], bfr[4];
    #pragma unroll
    for (int ai=0;ai<4;ai++) af[ai]  = *(const bf16x8*)&Ab[db][wr*4+ai][l][0];
    #pragma unroll
    for (int bj=0;bj<4;bj++) bfr[bj] = *(const bf16x8*)&Bb[db][wc*4+bj][l][0];
    #pragma unroll
    for (int ai=0;ai<4;ai++)
      #pragma unroll
      for (int bj=0;bj<4;bj++)
        acc[ai][bj] = MFMA16(af[ai], bfr[bj], acc[ai][bj]);
    __syncthreads();
  }
#undef QSTAGE

  const int chunk = o0 >> 10;
  const int hh    = (o0 >> 7) & 7;

  float rn[4][4];
  #pragma unroll
  for (int ai=0;ai<4;ai++)
    #pragma unroll
    for (int r=0;r<4;r++){
      float ss = 0.f;
      #pragma unroll
      for (int bj=0;bj<4;bj++) ss += acc[ai][bj][r]*acc[ai][bj][r];
      ss += __shfl_xor(ss, 1); ss += __shfl_xor(ss, 2);
      ss += __shfl_xor(ss, 4); ss += __shfl_xor(ss, 8);
      if (fr == 0) nbuf[wr*64 + ai*16 + g*4 + r][wc] = ss;
      rn[ai][r] = ss;
    }
  __syncthreads();
  #pragma unroll
  for (int ai=0;ai<4;ai++)
    #pragma unroll
    for (int r=0;r<4;r++){
      int row = wr*64 + ai*16 + g*4 + r;
      rn[ai][r] = rsqrtf(nbuf[row][0] + nbuf[row][1]);
    }

  #pragma unroll
  for (int ai=0;ai<4;ai++)
    #pragma unroll
    for (int r=0;r<4;r++){
      int n   = m0 + wr*64 + ai*16 + g*4 + r;
      size_t base = ((size_t)hh*NTOK + n)*128;
      #pragma unroll
      for (int bj=0;bj<4;bj++){
        int col = wc*64 + bj*16 + fr;
        float val = acc[ai][bj][r];
        short nv  = f2bf(val * rn[ai][r]);
        switch(chunk){
          case 0: qc[base+col] = nv; break;
          case 1: kc[base+col] = nv; break;
          case 3: qr[base+col] = nv; break;
          case 4: kr[base+col] = nv; break;
          default:
            vn[base+col] = nv;
            vb[base+col] = f2bf(val);
            out[(size_t)n*2048 + 1024 + hh*128 + col] = val;
            break;
        }
      }
    }
}

// ---------------------------------------------------------------------------
// Kernel 3: transpose raw v (bf16) [h][n][d] -> vT [h][d][n]
// ---------------------------------------------------------------------------
__global__ __launch_bounds__(256,4) void k_vT(
    const short* __restrict__ vb, short* __restrict__ vT)
{
  int b = blockIdx.x;
  int h  = b >> 6;
  int nt = (b >> 1) & 31;
  int dt = b & 1;
  __shared__ short t[64][72];
  int tid = threadIdx.x;
  int r  = tid >> 2;
  int c0 = (tid & 3) << 4;
  #pragma unroll
  for (int u=0;u<2;u++){
    bf16x8 val = *(const bf16x8*)&vb[((size_t)h*NTOK + nt*64 + r)*128 + dt*64 + c0 + u*8];
    #pragma unroll
    for (int e=0;e<8;e++) t[r][c0+u*8+e] = val[e];
  }
  __syncthreads();
  #pragma unroll
  for (int u=0;u<2;u++){
    bf16x8 o;
    #pragma unroll
    for (int e=0;e<8;e++) o[e] = t[c0+u*8+e][r];
    *(bf16x8*)&vT[((size_t)h*128 + dt*64 + r)*NTOK + nt*64 + c0 + u*8] = o;
  }
}

// ---------------------------------------------------------------------------
// Kernel 4: attention partial pass. R16 structure with Vbuf DELETED:
// V fragments loaded per-ks directly from frag-major vT global (coalesced,
// L2-resident via the (h,s)-per-XCD swizzle), issued before the ks's QK
// chain so the ~200cy L2 latency hides under 16 MFMA + exp. K staging via
// gld16 double-buffer unchanged. LDS 64KB -> 32KB; ds_reads/wave/iter halve.
// ---------------------------------------------------------------------------
#define JLEN 1024

__global__ __launch_bounds__(256,2) void k_attn(
    const short* __restrict__ qc, const short* __restrict__ kc,
    const short* __restrict__ qr, const short* __restrict__ kr,
    const short* __restrict__ vT,
    const float* __restrict__ csc, const float* __restrict__ fsc,
    float* __restrict__ s_cls, float* __restrict__ s_reg,
    short* __restrict__ Up)
{
  const int tid = threadIdx.x;
  const int l   = tid & 63;
  const int w   = tid >> 6;
  const int L    = blockIdx.x;            // 0..511
  const int xcd  = L & 7;
  const int slot = L >> 3;                // 0..63
  const int hs   = ((slot >> 5) << 3) | xcd;   // 0..15
  const int h    = hs >> 1;
  const int s    = hs & 1;
  const int rem  = slot & 31;
  const int js   = rem >> 4;
  const int ib   = rem & 15;

  const int iw  = ib * 128 + w * 32;
  const int fr  = l & 15;
  const int g   = l >> 4;
  const int fk8 = g * 8;
  const size_t hN = (size_t)h * NTOK;
  const size_t hD = (size_t)h * 128;

  const short* Qp = s ? qr : qc;
  const short* Kp = s ? kr : kc;
  const float* sc = s ? fsc : csc;
  float* ssum     = s ? s_reg : s_cls;
  short* Ub       = Up + (size_t)(js*2 + s) * 2097152;

  __shared__ __align__(16) short Kbuf[2][4][4][64][8];   // 32KB (double)

  const int t4 = w * 4;   // 16 K fragments, 4 per wave

#define STAGE(DB, JN) do {                                                   \
    _Pragma("unroll")                                                        \
    for (int q4=0; q4<4; ++q4){                                              \
      int t = t4 + q4;                                                       \
      int jf = t >> 2, kk = t & 3;                                           \
      gld16(Kp + (hN + (JN) + jf*16 + fr)*128 + kk*32 + fk8,                 \
            &Kbuf[DB][jf][kk][0][0]);                                        \
    }                                                                        \
  } while(0)

  bf16x8 bq[2][4];
  #pragma unroll
  for (int i2=0;i2<2;i2++)
    #pragma unroll
    for (int kk=0;kk<4;kk++)
      bq[i2][kk] = *(const bf16x8*)&Qp[(hN + iw + i2*16 + fr)*128 + kk*32 + fk8];

  float sci[2];
  sci[0] = sc[iw + fr] - 0.1f;
  sci[1] = sc[iw + 16 + fr] - 0.1f;

  f32x4 U[2][8] = {};
  float p[2] = {0.f, 0.f};

  const int srcA = ((((g<<1)    & 3) << 4) + fr) << 2;
  const int srcB = ((((g<<1 | 1)& 3) << 4) + fr) << 2;
  const bool ghi = g >= 2;
  const int jbase = js * JLEN;

  STAGE(0, jbase);
  __syncthreads();

  for (int jt = 0; jt < 16; ++jt){
    const int db = jt & 1;
    const int j0 = jbase + jt*64;
    if (jt < 15){ if (db) STAGE(0, j0 + 64); else STAGE(1, j0 + 64); }
    #pragma unroll
    for (int ks=0; ks<2; ++ks){
      // V fragments for this ks: direct global loads (frag-major vT),
      // issued before the QK chain so L2 latency hides under compute.
      bf16x8 bv[8];
      #pragma unroll
      for (int df=0; df<8; ++df)
        bv[df] = *(const bf16x8*)&vT[(hD + df*16 + fr)*2048 + j0 + ks*32 + fk8];

      int cpk[2][2][2];             // [i2][subtile t][pair]
      #pragma unroll
      for (int t=0; t<2; ++t){
        const int jf = ks*2 + t;
        f32x4 S0 = {}; f32x4 S1 = {};
        __builtin_amdgcn_s_setprio(1);
        #pragma unroll
        for (int kk=0; kk<4; ++kk){
          bf16x8 kb = *(const bf16x8*)&Kbuf[db][jf][kk][l][0];
          S0 = MFMA16(kb, bq[0][kk], S0);   // S^T: row=j, col=i
          S1 = MFMA16(kb, bq[1][kk], S1);
        }
        __builtin_amdgcn_s_setprio(0);
        float4 sjv = *(const float4*)&sc[j0 + jf*16 + 4*g];
        float e0[4], e1[4];
        #pragma unroll
        for (int r=0;r<4;r++){
          float sj = (&sjv.x)[r];
          float sj25 = 25.0f * sj;
          e0[r] = (sj > sci[0]) ? __expf(S0[r]*sj25) : 1.0f;
          e1[r] = (sj > sci[1]) ? __expf(S1[r]*sj25) : 1.0f;
          p[0] += e0[r]; p[1] += e1[r];
        }
        cpk[0][t][0] = cvtpk(e0[0], e0[1]);
        cpk[0][t][1] = cvtpk(e0[2], e0[3]);
        cpk[1][t][0] = cvtpk(e1[0], e1[1]);
        cpk[1][t][1] = cvtpk(e1[2], e1[3]);
      }
      bf16x8 ea[2];
      #pragma unroll
      for (int i2=0;i2<2;i2++){
        int a0 = __builtin_amdgcn_ds_bpermute(srcA, cpk[i2][0][0]);
        int a1 = __builtin_amdgcn_ds_bpermute(srcA, cpk[i2][0][1]);
        int a2 = __builtin_amdgcn_ds_bpermute(srcA, cpk[i2][1][0]);
        int a3 = __builtin_amdgcn_ds_bpermute(srcA, cpk[i2][1][1]);
        int b0 = __builtin_amdgcn_ds_bpermute(srcB, cpk[i2][0][0]);
        int b1 = __builtin_amdgcn_ds_bpermute(srcB, cpk[i2][0][1]);
        int b2 = __builtin_amdgcn_ds_bpermute(srcB, cpk[i2][1][0]);
        int b3 = __builtin_amdgcn_ds_bpermute(srcB, cpk[i2][1][1]);
        int wd[4];
        wd[0] = ghi ? a2 : a0;  wd[1] = ghi ? a3 : a1;
        wd[2] = ghi ? b2 : b0;  wd[3] = ghi ? b3 : b1;
        ea[i2] = *(bf16x8*)wd;
      }
      __builtin_amdgcn_s_setprio(1);
      #pragma unroll
      for (int df=0; df<8; ++df){
        U[0][df] = MFMA16(ea[0], bv[df], U[0][df]);
        U[1][df] = MFMA16(ea[1], bv[df], U[1][df]);
      }
      __builtin_amdgcn_s_setprio(0);
    }
    __syncthreads();
  }
#undef STAGE

  #pragma unroll
  for (int i2=0;i2<2;i2++){
    p[i2] += __shfl_xor(p[i2], 16);
    p[i2] += __shfl_xor(p[i2], 32);
  }
  if (l < 16){
    atomAddF(&ssum[hN + iw + l],      p[0]);
    atomAddF(&ssum[hN + iw + 16 + l], p[1]);
  }
  #pragma unroll
  for (int i2=0;i2<2;i2++)
    #pragma unroll
    for (int df=0;df<8;df++)
      #pragma unroll
      for (int r=0;r<4;r++)
        Ub[(hN + iw + i2*16 + g*4 + r)*128 + df*16 + fr] = f2bf(U[i2][df][r]);
}

// ---------------------------------------------------------------------------
// Kernel 4b: combine bf16 partials -> out = 0.5*(sum Uc/sc + sum Ur/sr)
// ---------------------------------------------------------------------------
__global__ __launch_bounds__(256,8) void k_attn_fin(
    const short* __restrict__ Up,
    const float* __restrict__ s_cls, const float* __restrict__ s_reg,
    float* __restrict__ out)
{
  int task = blockIdx.x*4 + (threadIdx.x>>6);   // h*2048 + row
  int lane = threadIdx.x & 63;
  int h = task >> 11;
  int row = task & 2047;
  size_t b = (size_t)task*128 + lane*2;
  float cx=0.f, cy=0.f, rx=0.f, ry=0.f;
  #pragma unroll
  for (int js=0; js<2; ++js){
    s16x2 c = *(const s16x2*)(Up + (size_t)(js*2+0)*2097152 + b);
    s16x2 r = *(const s16x2*)(Up + (size_t)(js*2+1)*2097152 + b);
    cx += bf2f(c[0]); cy += bf2f(c[1]);
    rx += bf2f(r[0]); ry += bf2f(r[1]);
  }
  float isc = 0.5f/s_cls[task];
  float isr = 0.5f/s_reg[task];
  float2 o = { cx*isc + rx*isr, cy*isc + ry*isr };
  *(float2*)&out[(size_t)row*2048 + h*128 + lane*2] = o;
}

// ---------------------------------------------------------------------------
// Kernel 5: sim_attn (R16 structure, gld16 staging) — unchanged.
// ---------------------------------------------------------------------------
__global__ __launch_bounds__(256,2) void k_sim(
    const short* __restrict__ qc, const short* __restrict__ kc,
    const short* __restrict__ qr, const short* __restrict__ kr,
    const float* __restrict__ csc, const float* __restrict__ fsc,
    const float* __restrict__ s_cls, const float* __restrict__ s_reg,
    float* __restrict__ out)
{
  const int tid  = threadIdx.x;
  const int lane = tid & 63;
  const int w    = tid >> 6;
  const int i0w  = blockIdx.x * 128 + w * 32;
  const int j0   = blockIdx.y * 64;
  const int fr   = lane & 15;
  const int fk   = (lane >> 4) * 8;

  __shared__ __align__(16) short Bsh[2][16][64][8];   // 32 KiB

  float sjc[4], sjf[4];
  #pragma unroll
  for (int js=0;js<4;js++){ sjc[js]=csc[j0+js*16+fr]; sjf[js]=fsc[j0+js*16+fr]; }
  int rowb[2]; float sci[2][4], sfi[2][4];
  #pragma unroll
  for (int ri=0;ri<2;ri++){
    rowb[ri] = i0w + ri*16 + ((lane>>4)<<2);
    #pragma unroll
    for (int r=0;r<4;r++){ sci[ri][r]=csc[rowb[ri]+r]; sfi[ri][r]=fsc[rowb[ri]+r]; }
  }

  f32x4 sim[2][4] = {};

  for (int h=0; h<8; ++h){
    const size_t hb = (size_t)h * NTOK;
    __syncthreads();                    // prior head's LDS reads complete
    #pragma unroll
    for (int it=0; it<8; ++it){
      int t   = it*4 + w;               // 0..31
      int str = t >> 4;                 // 0=kc 1=kr
      int f   = t & 15;                 // frag index
      const short* gp = str ? kr : kc;
      int r = (f >> 2)*16 + fr;
      int c = (f & 3)*32 + fk;
      gld16(gp + (hb + j0 + r)*128 + c, &Bsh[str][f][0][0]);
    }
    bf16x8 aq[2][4], ar[2][4];
    #pragma unroll
    for (int ri=0;ri<2;ri++)
      #pragma unroll
      for (int kk=0;kk<4;kk++){
        aq[ri][kk] = *(const bf16x8*)&qc[(hb + i0w + ri*16 + fr)*128 + kk*32 + fk];
        ar[ri][kk] = *(const bf16x8*)&qr[(hb + i0w + ri*16 + fr)*128 + kk*32 + fk];
      }
    float iscl[2][4], isrl[2][4];
    #pragma unroll
    for (int ri=0;ri<2;ri++)
      #pragma unroll
      for (int r=0;r<4;r++){
        iscl[ri][r] = 1.0f/s_cls[hb + rowb[ri] + r];
        isrl[ri][r] = 1.0f/s_reg[hb + rowb[ri] + r];
      }
    __syncthreads();                    // drains gld16s
    #pragma unroll
    for (int js=0; js<4; ++js){
      bf16x8 bc[4], br[4];
      #pragma unroll
      for (int kk=0;kk<4;kk++){
        bc[kk] = *(const bf16x8*)&Bsh[0][js*4+kk][lane][0];
        br[kk] = *(const bf16x8*)&Bsh[1][js*4+kk][lane][0];
      }
      #pragma unroll
      for (int ri=0;ri<2;ri++){
        f32x4 Sc = {}; f32x4 Sr = {};
        __builtin_amdgcn_s_setprio(1);
        #pragma unroll
        for (int kk=0;kk<4;kk++){
          Sc = MFMA16(aq[ri][kk], bc[kk], Sc);
          Sr = MFMA16(ar[ri][kk], br[kk], Sr);
        }
        __builtin_amdgcn_s_setprio(0);
        #pragma unroll
        for (int r=0;r<4;r++){
          float ec = (sjc[js] > sci[ri][r]-0.1f) ? __expf(Sc[r]*(25.0f*sjc[js])) : 1.0f;
          float er = (sjf[js] > sfi[ri][r]-0.1f) ? __expf(Sr[r]*(25.0f*sjf[js])) : 1.0f;
          sim[ri][js][r] += ec*iscl[ri][r] + er*isrl[ri][r];
        }
      }
    }
  }
  #pragma unroll
  for (int ri=0;ri<2;ri++)
    #pragma unroll
    for (int js=0;js<4;js++)
      #pragma unroll
      for (int r=0;r<4;r++)
        out[4194304ull + (size_t)(rowb[ri]+r)*2048 + j0 + js*16 + fr]
            = sim[ri][js][r] * 0.0625f;
}

// ---------------------------------------------------------------------------
// Kernel 5b: raw = Vn . Vn^T over full C=1024; mask = raw>6.  gld16 staging.
// ---------------------------------------------------------------------------
__global__ __launch_bounds__(256,4) void k_raw(
    const short* __restrict__ vn, unsigned char* __restrict__ mask)
{
  const int tid  = threadIdx.x;
  const int lane = tid & 63;
  const int w    = tid >> 6;
  const int i0w  = blockIdx.x * 128 + w * 32;
  const int j0   = blockIdx.y * 64;
  const int fr   = lane & 15;
  const int fk   = (lane >> 4) * 8;

  __shared__ __align__(16) short Bsh[16][64][8];   // 16 KiB

  f32x4 raw[2][4] = {};

  for (int cc=0; cc<8; ++cc){
    const size_t hb = (size_t)cc * NTOK;
    __syncthreads();
    #pragma unroll
    for (int it=0; it<4; ++it){
      int f = it*4 + w;                 // 0..15
      int r = (f >> 2)*16 + fr;
      int c = (f & 3)*32 + fk;
      gld16(vn + (hb + j0 + r)*128 + c, &Bsh[f][0][0]);
    }
    bf16x8 av[2][4];
    #pragma unroll
    for (int ri=0;ri<2;ri++)
      #pragma unroll
      for (int kk=0;kk<4;kk++)
        av[ri][kk] = *(const bf16x8*)&vn[(hb + i0w + ri*16 + fr)*128 + kk*32 + fk];
    __syncthreads();
    #pragma unroll
    for (int js=0; js<4; ++js){
      bf16x8 bv[4];
      #pragma unroll
      for (int kk=0;kk<4;kk++) bv[kk] = *(const bf16x8*)&Bsh[js*4+kk][lane][0];
      #pragma unroll
      for (int ri=0;ri<2;ri++)
        #pragma unroll
        for (int kk=0;kk<4;kk++)
          raw[ri][js] = MFMA16(av[ri][kk], bv[kk], raw[ri][js]);
    }
  }
  const int rb0 = i0w + ((lane>>4)<<2);
  #pragma unroll
  for (int ri=0;ri<2;ri++)
    #pragma unroll
    for (int js=0;js<4;js++)
      #pragma unroll
      for (int r=0;r<4;r++)
        mask[(size_t)(rb0 + ri*16 + r)*2048 + j0 + js*16 + fr]
            = raw[ri][js][r] > 6.0f ? 1 : 0;
}

// ---------------------------------------------------------------------------
// Kernel 6: final masked renorm (in place on sim half of out).
// ---------------------------------------------------------------------------
__global__ __launch_bounds__(256,4) void k_final(
    float* __restrict__ out, const unsigned char* __restrict__ mask)
{
  int row  = blockIdx.x*4 + (threadIdx.x>>6);
  int lane = threadIdx.x & 63;
  float* sr = out + 4194304ull + (size_t)row*2048;
  const unsigned char* mr = mask + (size_t)row*2048;
  float v[32];
  float sum2 = 0.0f;
  #pragma unroll
  for (int c=0;c<32;c++){
    float e = __expf(sr[c*64 + lane]);
    v[c] = (mr[c*64 + lane] != 0) ? e : 0.0f;
    sum2 += v[c];
  }
  #pragma unroll
  for (int m=1;m<64;m<<=1) sum2 += __shfl_xor(sum2, m);
  float inv = 1.0f / sum2;
  #pragma unroll
  for (int c=0;c<32;c++) sr[c*64 + lane] = v[c]*inv;
}

// ---------------------------------------------------------------------------
extern "C" void kernel_launch(void* const* d_in, const int* in_sizes, int n_in,
                              void* d_out, int out_size, void* d_ws, size_t ws_size,
                              hipStream_t stream)
{
  const float* xcls = (const float*)d_in[0];
  const float* xreg = (const float*)d_in[1];
  const float* csc  = (const float*)d_in[2];
  const float* fsc  = (const float*)d_in[3];
  const float* Wc   = (const float*)d_in[4];
  const float* Wr   = (const float*)d_in[5];
  float* out = (float*)d_out;

  char* ws = (char*)d_ws;
  short* xbc = (short*)ws;
  short* xbr = xbc + 2097152;
  short* wbc = xbr + 2097152;           // 3145728 shorts
  short* wbr = wbc + 3145728;
  unsigned char* mask = (unsigned char*)ws;
  char* accbase       = ws + 4u*1024*1024;
  float* s_cls        = (float*)(accbase);
  float* s_reg        = (float*)(accbase + 65536);
  short* Up           = (short*)(accbase + 131072);   // 4 x 4.19MB bf16 partials
  short* qc = (short*)(ws + 41943040ull);
  short* kc = qc + 2097152;
  short* qr = kc + 2097152;
  short* kr = qr + 2097152;
  short* vn = kr + 2097152;
  short* vb = vn + 2097152;
  short* vT = vb + 2097152;

  k_cvt  <<<4608,        256, 0, stream>>>(xcls, xreg, Wc, Wr, xbc, xbr, wbc, wbr);
  k_qkv  <<<640,         256, 0, stream>>>(xbc, xbr, wbc, wbr,
                                           qc, kc, qr, kr, vn, vb, out);
  k_vT   <<<512,         256, 0, stream>>>(vb, vT);
  hipMemsetAsync(accbase, 0, 131072, stream);   // zero s_cls/s_reg only
  k_attn <<<512,         256, 0, stream>>>(qc, kc, qr, kr, vT, csc, fsc,
                                           s_cls, s_reg, Up);
  k_attn_fin <<<4096,    256, 0, stream>>>(Up, s_cls, s_reg, out);
  k_raw  <<<dim3(16,32), 256, 0, stream>>>(vn, mask);
  k_sim  <<<dim3(16,32), 256, 0, stream>>>(qc, kc, qr, kr, csc, fsc,
                                           s_cls, s_reg, out);
  k_final<<<512,         256, 0, stream>>>(out, mask);
}

// Round 18
// 241.948 us; speedup vs baseline: 1.1540x; 1.1540x over previous
//
#include <hip/hip_runtime.h>

// ---------------------------------------------------------------------------
// Attention_msa: B=1, N=2048, C=1024, H=8, d=128, SCALE=25, SIM_THRESH=0.75
// R16 configuration (session best: 242.3 us) — restored verbatim.
// ---------------------------------------------------------------------------

#define NTOK 2048
#define CDIM 1024

typedef __attribute__((ext_vector_type(8))) short bf16x8;
typedef __attribute__((ext_vector_type(4))) short s16x4;
typedef __attribute__((ext_vector_type(2))) short s16x2;
typedef __attribute__((ext_vector_type(4))) float f32x4;

#define MFMA16(a,b,c) __builtin_amdgcn_mfma_f32_16x16x32_bf16((a),(b),(c),0,0,0)

__device__ __forceinline__ short f2bf(float x){
  unsigned u = __float_as_uint(x);
  u += 0x7FFFu + ((u >> 16) & 1u);           // round-to-nearest-even
  return (short)(u >> 16);
}

__device__ __forceinline__ float bf2f(short s){
  return __uint_as_float(((unsigned)(unsigned short)s) << 16);
}

__device__ __forceinline__ int cvtpk(float lo, float hi){
  int r;
  asm("v_cvt_pk_bf16_f32 %0, %1, %2" : "=v"(r) : "v"(lo), "v"(hi));
  return r;
}

__device__ __forceinline__ void atomAddF(float* p, float v){
  unsafeAtomicAdd(p, v);                     // global_atomic_add_f32
}

// async global->LDS, 16B per lane; LDS dest = uniform base + lane*16
__device__ __forceinline__ void gld16(const short* g, short* l){
  __builtin_amdgcn_global_load_lds(
      (const __attribute__((address_space(1))) unsigned int*)g,
      (__attribute__((address_space(3))) unsigned int*)l, 16, 0, 0);
}

// ---------------------------------------------------------------------------
// Kernel 0: f32 -> bf16 conversion of GEMM inputs (one pass).
// ---------------------------------------------------------------------------
__global__ __launch_bounds__(256,8) void k_cvt(
    const float* __restrict__ xc, const float* __restrict__ xr,
    const float* __restrict__ Wc, const float* __restrict__ Wr,
    short* __restrict__ xbc, short* __restrict__ xbr,
    short* __restrict__ wbc, short* __restrict__ wbr)
{
  int idx = blockIdx.x*256 + threadIdx.x;    // 0..1179647
  const float* src; short* dst; int off;
  if      (idx <  262144){ src = xc; dst = xbc; off = idx; }
  else if (idx <  524288){ src = xr; dst = xbr; off = idx - 262144; }
  else if (idx <  917504){ src = Wc; dst = wbc; off = idx - 524288; }
  else                   { src = Wr; dst = wbr; off = idx - 917504; }
  float4 a = *(const float4*)(src + (size_t)off*8);
  float4 b = *(const float4*)(src + (size_t)off*8 + 4);
  bf16x8 o = { f2bf(a.x), f2bf(a.y), f2bf(a.z), f2bf(a.w),
               f2bf(b.x), f2bf(b.y), f2bf(b.z), f2bf(b.w) };
  *(bf16x8*)(dst + (size_t)off*8) = o;
}

// ---------------------------------------------------------------------------
// Kernel 1: QKV GEMM + FUSED per-head L2 norm.
// ---------------------------------------------------------------------------
__global__ __launch_bounds__(256,3) void k_qkv(
    const short* __restrict__ xbc, const short* __restrict__ xbr,
    const short* __restrict__ wbc, const short* __restrict__ wbr,
    short* __restrict__ qc, short* __restrict__ kc,
    short* __restrict__ qr, short* __restrict__ kr,
    short* __restrict__ vn, short* __restrict__ vb,
    float* __restrict__ out)
{
  const int tid = threadIdx.x;
  const int l   = tid & 63;
  const int w   = tid >> 6;
  const int fr  = l & 15;
  const int g   = l >> 4;
  const int fk8 = g * 8;

  const int L     = blockIdx.x;
  const int xcd   = L & 7;
  const int slot  = L >> 3;              // 0..79
  const int panel = xcd*5 + (slot >> 4); // 0..39
  const int mb    = slot & 15;
  const int m0    = mb * 128;
  const int o0    = panel * 128;

  const short* Xb; const short* Wb; int wrow;
  if (o0 < 3072){ Xb = xbc; Wb = wbc; wrow = o0; }
  else          { Xb = xbr; Wb = wbr; wrow = o0 - 3072; }

  __shared__ __align__(16) short Ab[2][8][64][8];   // 16KB (double)
  __shared__ __align__(16) short Bb[2][8][64][8];   // 16KB (double)
  __shared__ float nbuf[128][2];

  const int wr = w >> 1;
  const int wc = w & 1;

#define QSTAGE(DB, KN) do {                                                  \
    _Pragma("unroll")                                                        \
    for (int it=0; it<2; ++it){                                              \
      int f = it*4 + w;                                                      \
      gld16(Xb + (size_t)(m0  + f*16 + fr)*CDIM + (KN) + fk8,                \
            &Ab[DB][f][0][0]);                                               \
      gld16(Wb + (size_t)(wrow + f*16 + fr)*CDIM + (KN) + fk8,               \
            &Bb[DB][f][0][0]);                                               \
    }                                                                        \
  } while(0)

  f32x4 acc[4][4] = {};

  QSTAGE(0, 0);
  __syncthreads();

  for (int kt = 0; kt < 32; ++kt){
    const int db = kt & 1;
    if (kt < 31){ if (db) QSTAGE(0, (kt+1)*32); else QSTAGE(1, (kt+1)*32); }
    bf16x8 af[4], bfr[4];
    #pragma unroll
    for (int ai=0;ai<4;ai++) af[ai]  = *(const bf16x8*)&Ab[db][wr*4+ai][l][0];
    #pragma unroll
    for (int bj=0;bj<4;bj++) bfr[bj] = *(const bf16x8*)&Bb[db][wc*4+bj][l][0];
    #pragma unroll
    for (int ai=0;ai<4;ai++)
      #pragma unroll
      for (int bj=0;bj<4;bj++)
        acc[ai][bj] = MFMA16(af[ai], bfr[bj], acc[ai][bj]);
    __syncthreads();
  }
#undef QSTAGE

  const int chunk = o0 >> 10;
  const int hh    = (o0 >> 7) & 7;

  float rn[4][4];
  #pragma unroll
  for (int ai=0;ai<4;ai++)
    #pragma unroll
    for (int r=0;r<4;r++){
      float ss = 0.f;
      #pragma unroll
      for (int bj=0;bj<4;bj++) ss += acc[ai][bj][r]*acc[ai][bj][r];
      ss += __shfl_xor(ss, 1); ss += __shfl_xor(ss, 2);
      ss += __shfl_xor(ss, 4); ss += __shfl_xor(ss, 8);
      if (fr == 0) nbuf[wr*64 + ai*16 + g*4 + r][wc] = ss;
      rn[ai][r] = ss;
    }
  __syncthreads();
  #pragma unroll
  for (int ai=0;ai<4;ai++)
    #pragma unroll
    for (int r=0;r<4;r++){
      int row = wr*64 + ai*16 + g*4 + r;
      rn[ai][r] = rsqrtf(nbuf[row][0] + nbuf[row][1]);
    }

  #pragma unroll
  for (int ai=0;ai<4;ai++)
    #pragma unroll
    for (int r=0;r<4;r++){
      int n   = m0 + wr*64 + ai*16 + g*4 + r;
      size_t base = ((size_t)hh*NTOK + n)*128;
      #pragma unroll
      for (int bj=0;bj<4;bj++){
        int col = wc*64 + bj*16 + fr;
        float val = acc[ai][bj][r];
        short nv  = f2bf(val * rn[ai][r]);
        switch(chunk){
          case 0: qc[base+col] = nv; break;
          case 1: kc[base+col] = nv; break;
          case 3: qr[base+col] = nv; break;
          case 4: kr[base+col] = nv; break;
          default:
            vn[base+col] = nv;
            vb[base+col] = f2bf(val);
            out[(size_t)n*2048 + 1024 + hh*128 + col] = val;
            break;
        }
      }
    }
}

// ---------------------------------------------------------------------------
// Kernel 3: transpose raw v (bf16) [h][n][d] -> vT [h][d][n]
// ---------------------------------------------------------------------------
__global__ __launch_bounds__(256,4) void k_vT(
    const short* __restrict__ vb, short* __restrict__ vT)
{
  int b = blockIdx.x;
  int h  = b >> 6;
  int nt = (b >> 1) & 31;
  int dt = b & 1;
  __shared__ short t[64][72];
  int tid = threadIdx.x;
  int r  = tid >> 2;
  int c0 = (tid & 3) << 4;
  #pragma unroll
  for (int u=0;u<2;u++){
    bf16x8 val = *(const bf16x8*)&vb[((size_t)h*NTOK + nt*64 + r)*128 + dt*64 + c0 + u*8];
    #pragma unroll
    for (int e=0;e<8;e++) t[r][c0+u*8+e] = val[e];
  }
  __syncthreads();
  #pragma unroll
  for (int u=0;u<2;u++){
    bf16x8 o;
    #pragma unroll
    for (int e=0;e<8;e++) o[e] = t[c0+u*8+e][r];
    *(bf16x8*)&vT[((size_t)h*128 + dt*64 + r)*NTOK + nt*64 + c0 + u*8] = o;
  }
}

// ---------------------------------------------------------------------------
// Kernel 4: attention partial pass — R16 structure (K + V staged via gld16
// double-buffer, 64KB LDS, swapped QK^T, in-register E, bf16 Up partials).
// ---------------------------------------------------------------------------
#define JLEN 1024

__global__ __launch_bounds__(256,2) void k_attn(
    const short* __restrict__ qc, const short* __restrict__ kc,
    const short* __restrict__ qr, const short* __restrict__ kr,
    const short* __restrict__ vT,
    const float* __restrict__ csc, const float* __restrict__ fsc,
    float* __restrict__ s_cls, float* __restrict__ s_reg,
    short* __restrict__ Up)
{
  const int tid = threadIdx.x;
  const int l   = tid & 63;
  const int w   = tid >> 6;
  const int L    = blockIdx.x;            // 0..511
  const int xcd  = L & 7;
  const int slot = L >> 3;                // 0..63
  const int hs   = ((slot >> 5) << 3) | xcd;   // 0..15
  const int h    = hs >> 1;
  const int s    = hs & 1;
  const int rem  = slot & 31;
  const int js   = rem >> 4;
  const int ib   = rem & 15;

  const int iw  = ib * 128 + w * 32;
  const int fr  = l & 15;
  const int g   = l >> 4;
  const int fk8 = g * 8;
  const size_t hN = (size_t)h * NTOK;
  const size_t hD = (size_t)h * 128;

  const short* Qp = s ? qr : qc;
  const short* Kp = s ? kr : kc;
  const float* sc = s ? fsc : csc;
  float* ssum     = s ? s_reg : s_cls;
  short* Ub       = Up + (size_t)(js*2 + s) * 2097152;

  __shared__ __align__(16) short Kbuf[2][4][4][64][8];   // 32KB (double)
  __shared__ __align__(16) short Vbuf[2][8][2][64][8];   // 32KB (double)

  const int t8 = w * 8;

#define STAGE(DB, JN) do {                                                   \
    _Pragma("unroll")                                                        \
    for (int q8=0; q8<8; ++q8){                                              \
      int t = t8 + q8;                                                       \
      if (t < 16){                                                           \
        int jf = t >> 2, kk = t & 3;                                         \
        gld16(Kp + (hN + (JN) + jf*16 + fr)*128 + kk*32 + fk8,               \
              &Kbuf[DB][jf][kk][0][0]);                                      \
      } else {                                                               \
        int u = t - 16, df = u >> 1, ks = u & 1;                             \
        gld16(vT + (hD + df*16 + fr)*2048 + (JN) + ks*32 + fk8,              \
              &Vbuf[DB][df][ks][0][0]);                                      \
      }                                                                      \
    }                                                                        \
  } while(0)

  bf16x8 bq[2][4];
  #pragma unroll
  for (int i2=0;i2<2;i2++)
    #pragma unroll
    for (int kk=0;kk<4;kk++)
      bq[i2][kk] = *(const bf16x8*)&Qp[(hN + iw + i2*16 + fr)*128 + kk*32 + fk8];

  float sci[2];
  sci[0] = sc[iw + fr] - 0.1f;
  sci[1] = sc[iw + 16 + fr] - 0.1f;

  f32x4 U[2][8] = {};
  float p[2] = {0.f, 0.f};

  const int srcA = ((((g<<1)    & 3) << 4) + fr) << 2;
  const int srcB = ((((g<<1 | 1)& 3) << 4) + fr) << 2;
  const bool ghi = g >= 2;
  const int jbase = js * JLEN;

  STAGE(0, jbase);
  __syncthreads();

  for (int jt = 0; jt < 16; ++jt){
    const int db = jt & 1;
    const int j0 = jbase + jt*64;
    if (jt < 15){ if (db) STAGE(0, j0 + 64); else STAGE(1, j0 + 64); }
    #pragma unroll
    for (int ks=0; ks<2; ++ks){
      int cpk[2][2][2];             // [i2][subtile t][pair]
      #pragma unroll
      for (int t=0; t<2; ++t){
        const int jf = ks*2 + t;
        f32x4 S0 = {}; f32x4 S1 = {};
        __builtin_amdgcn_s_setprio(1);
        #pragma unroll
        for (int kk=0; kk<4; ++kk){
          bf16x8 kb = *(const bf16x8*)&Kbuf[db][jf][kk][l][0];
          S0 = MFMA16(kb, bq[0][kk], S0);   // S^T: row=j, col=i
          S1 = MFMA16(kb, bq[1][kk], S1);
        }
        __builtin_amdgcn_s_setprio(0);
        float4 sjv = *(const float4*)&sc[j0 + jf*16 + 4*g];
        float e0[4], e1[4];
        #pragma unroll
        for (int r=0;r<4;r++){
          float sj = (&sjv.x)[r];
          float sj25 = 25.0f * sj;
          e0[r] = (sj > sci[0]) ? __expf(S0[r]*sj25) : 1.0f;
          e1[r] = (sj > sci[1]) ? __expf(S1[r]*sj25) : 1.0f;
          p[0] += e0[r]; p[1] += e1[r];
        }
        cpk[0][t][0] = cvtpk(e0[0], e0[1]);
        cpk[0][t][1] = cvtpk(e0[2], e0[3]);
        cpk[1][t][0] = cvtpk(e1[0], e1[1]);
        cpk[1][t][1] = cvtpk(e1[2], e1[3]);
      }
      bf16x8 ea[2];
      #pragma unroll
      for (int i2=0;i2<2;i2++){
        int a0 = __builtin_amdgcn_ds_bpermute(srcA, cpk[i2][0][0]);
        int a1 = __builtin_amdgcn_ds_bpermute(srcA, cpk[i2][0][1]);
        int a2 = __builtin_amdgcn_ds_bpermute(srcA, cpk[i2][1][0]);
        int a3 = __builtin_amdgcn_ds_bpermute(srcA, cpk[i2][1][1]);
        int b0 = __builtin_amdgcn_ds_bpermute(srcB, cpk[i2][0][0]);
        int b1 = __builtin_amdgcn_ds_bpermute(srcB, cpk[i2][0][1]);
        int b2 = __builtin_amdgcn_ds_bpermute(srcB, cpk[i2][1][0]);
        int b3 = __builtin_amdgcn_ds_bpermute(srcB, cpk[i2][1][1]);
        int wd[4];
        wd[0] = ghi ? a2 : a0;  wd[1] = ghi ? a3 : a1;
        wd[2] = ghi ? b2 : b0;  wd[3] = ghi ? b3 : b1;
        ea[i2] = *(bf16x8*)wd;
      }
      __builtin_amdgcn_s_setprio(1);
      #pragma unroll
      for (int df=0; df<8; ++df){
        bf16x8 bv = *(const bf16x8*)&Vbuf[db][df][ks][l][0];
        U[0][df] = MFMA16(ea[0], bv, U[0][df]);
        U[1][df] = MFMA16(ea[1], bv, U[1][df]);
      }
      __builtin_amdgcn_s_setprio(0);
    }
    __syncthreads();
  }
#undef STAGE

  #pragma unroll
  for (int i2=0;i2<2;i2++){
    p[i2] += __shfl_xor(p[i2], 16);
    p[i2] += __shfl_xor(p[i2], 32);
  }
  if (l < 16){
    atomAddF(&ssum[hN + iw + l],      p[0]);
    atomAddF(&ssum[hN + iw + 16 + l], p[1]);
  }
  #pragma unroll
  for (int i2=0;i2<2;i2++)
    #pragma unroll
    for (int df=0;df<8;df++)
      #pragma unroll
      for (int r=0;r<4;r++)
        Ub[(hN + iw + i2*16 + g*4 + r)*128 + df*16 + fr] = f2bf(U[i2][df][r]);
}

// ---------------------------------------------------------------------------
// Kernel 4b: combine bf16 partials -> out = 0.5*(sum Uc/sc + sum Ur/sr)
// ---------------------------------------------------------------------------
__global__ __launch_bounds__(256,8) void k_attn_fin(
    const short* __restrict__ Up,
    const float* __restrict__ s_cls, const float* __restrict__ s_reg,
    float* __restrict__ out)
{
  int task = blockIdx.x*4 + (threadIdx.x>>6);   // h*2048 + row
  int lane = threadIdx.x & 63;
  int h = task >> 11;
  int row = task & 2047;
  size_t b = (size_t)task*128 + lane*2;
  float cx=0.f, cy=0.f, rx=0.f, ry=0.f;
  #pragma unroll
  for (int js=0; js<2; ++js){
    s16x2 c = *(const s16x2*)(Up + (size_t)(js*2+0)*2097152 + b);
    s16x2 r = *(const s16x2*)(Up + (size_t)(js*2+1)*2097152 + b);
    cx += bf2f(c[0]); cy += bf2f(c[1]);
    rx += bf2f(r[0]); ry += bf2f(r[1]);
  }
  float isc = 0.5f/s_cls[task];
  float isr = 0.5f/s_reg[task];
  float2 o = { cx*isc + rx*isr, cy*isc + ry*isr };
  *(float2*)&out[(size_t)row*2048 + h*128 + lane*2] = o;
}

// ---------------------------------------------------------------------------
// Kernel 5: sim_attn (128i x 64j, grid (16,32), gld16 staging).
// ---------------------------------------------------------------------------
__global__ __launch_bounds__(256,2) void k_sim(
    const short* __restrict__ qc, const short* __restrict__ kc,
    const short* __restrict__ qr, const short* __restrict__ kr,
    const float* __restrict__ csc, const float* __restrict__ fsc,
    const float* __restrict__ s_cls, const float* __restrict__ s_reg,
    float* __restrict__ out)
{
  const int tid  = threadIdx.x;
  const int lane = tid & 63;
  const int w    = tid >> 6;
  const int i0w  = blockIdx.x * 128 + w * 32;
  const int j0   = blockIdx.y * 64;
  const int fr   = lane & 15;
  const int fk   = (lane >> 4) * 8;

  __shared__ __align__(16) short Bsh[2][16][64][8];   // 32 KiB

  float sjc[4], sjf[4];
  #pragma unroll
  for (int js=0;js<4;js++){ sjc[js]=csc[j0+js*16+fr]; sjf[js]=fsc[j0+js*16+fr]; }
  int rowb[2]; float sci[2][4], sfi[2][4];
  #pragma unroll
  for (int ri=0;ri<2;ri++){
    rowb[ri] = i0w + ri*16 + ((lane>>4)<<2);
    #pragma unroll
    for (int r=0;r<4;r++){ sci[ri][r]=csc[rowb[ri]+r]; sfi[ri][r]=fsc[rowb[ri]+r]; }
  }

  f32x4 sim[2][4] = {};

  for (int h=0; h<8; ++h){
    const size_t hb = (size_t)h * NTOK;
    __syncthreads();                    // prior head's LDS reads complete
    #pragma unroll
    for (int it=0; it<8; ++it){
      int t   = it*4 + w;               // 0..31
      int str = t >> 4;                 // 0=kc 1=kr
      int f   = t & 15;                 // frag index
      const short* gp = str ? kr : kc;
      int r = (f >> 2)*16 + fr;
      int c = (f & 3)*32 + fk;
      gld16(gp + (hb + j0 + r)*128 + c, &Bsh[str][f][0][0]);
    }
    bf16x8 aq[2][4], ar[2][4];
    #pragma unroll
    for (int ri=0;ri<2;ri++)
      #pragma unroll
      for (int kk=0;kk<4;kk++){
        aq[ri][kk] = *(const bf16x8*)&qc[(hb + i0w + ri*16 + fr)*128 + kk*32 + fk];
        ar[ri][kk] = *(const bf16x8*)&qr[(hb + i0w + ri*16 + fr)*128 + kk*32 + fk];
      }
    float iscl[2][4], isrl[2][4];
    #pragma unroll
    for (int ri=0;ri<2;ri++)
      #pragma unroll
      for (int r=0;r<4;r++){
        iscl[ri][r] = 1.0f/s_cls[hb + rowb[ri] + r];
        isrl[ri][r] = 1.0f/s_reg[hb + rowb[ri] + r];
      }
    __syncthreads();                    // drains gld16s
    #pragma unroll
    for (int js=0; js<4; ++js){
      bf16x8 bc[4], br[4];
      #pragma unroll
      for (int kk=0;kk<4;kk++){
        bc[kk] = *(const bf16x8*)&Bsh[0][js*4+kk][lane][0];
        br[kk] = *(const bf16x8*)&Bsh[1][js*4+kk][lane][0];
      }
      #pragma unroll
      for (int ri=0;ri<2;ri++){
        f32x4 Sc = {}; f32x4 Sr = {};
        __builtin_amdgcn_s_setprio(1);
        #pragma unroll
        for (int kk=0;kk<4;kk++){
          Sc = MFMA16(aq[ri][kk], bc[kk], Sc);
          Sr = MFMA16(ar[ri][kk], br[kk], Sr);
        }
        __builtin_amdgcn_s_setprio(0);
        #pragma unroll
        for (int r=0;r<4;r++){
          float ec = (sjc[js] > sci[ri][r]-0.1f) ? __expf(Sc[r]*(25.0f*sjc[js])) : 1.0f;
          float er = (sjf[js] > sfi[ri][r]-0.1f) ? __expf(Sr[r]*(25.0f*sjf[js])) : 1.0f;
          sim[ri][js][r] += ec*iscl[ri][r] + er*isrl[ri][r];
        }
      }
    }
  }
  #pragma unroll
  for (int ri=0;ri<2;ri++)
    #pragma unroll
    for (int js=0;js<4;js++)
      #pragma unroll
      for (int r=0;r<4;r++)
        out[4194304ull + (size_t)(rowb[ri]+r)*2048 + j0 + js*16 + fr]
            = sim[ri][js][r] * 0.0625f;
}

// ---------------------------------------------------------------------------
// Kernel 5b: raw = Vn . Vn^T over full C=1024; mask = raw>6.  gld16 staging.
// ---------------------------------------------------------------------------
__global__ __launch_bounds__(256,4) void k_raw(
    const short* __restrict__ vn, unsigned char* __restrict__ mask)
{
  const int tid  = threadIdx.x;
  const int lane = tid & 63;
  const int w    = tid >> 6;
  const int i0w  = blockIdx.x * 128 + w * 32;
  const int j0   = blockIdx.y * 64;
  const int fr   = lane & 15;
  const int fk   = (lane >> 4) * 8;

  __shared__ __align__(16) short Bsh[16][64][8];   // 16 KiB

  f32x4 raw[2][4] = {};

  for (int cc=0; cc<8; ++cc){
    const size_t hb = (size_t)cc * NTOK;
    __syncthreads();
    #pragma unroll
    for (int it=0; it<4; ++it){
      int f = it*4 + w;                 // 0..15
      int r = (f >> 2)*16 + fr;
      int c = (f & 3)*32 + fk;
      gld16(vn + (hb + j0 + r)*128 + c, &Bsh[f][0][0]);
    }
    bf16x8 av[2][4];
    #pragma unroll
    for (int ri=0;ri<2;ri++)
      #pragma unroll
      for (int kk=0;kk<4;kk++)
        av[ri][kk] = *(const bf16x8*)&vn[(hb + i0w + ri*16 + fr)*128 + kk*32 + fk];
    __syncthreads();
    #pragma unroll
    for (int js=0; js<4; ++js){
      bf16x8 bv[4];
      #pragma unroll
      for (int kk=0;kk<4;kk++) bv[kk] = *(const bf16x8*)&Bsh[js*4+kk][lane][0];
      #pragma unroll
      for (int ri=0;ri<2;ri++)
        #pragma unroll
        for (int kk=0;kk<4;kk++)
          raw[ri][js] = MFMA16(av[ri][kk], bv[kk], raw[ri][js]);
    }
  }
  const int rb0 = i0w + ((lane>>4)<<2);
  #pragma unroll
  for (int ri=0;ri<2;ri++)
    #pragma unroll
    for (int js=0;js<4;js++)
      #pragma unroll
      for (int r=0;r<4;r++)
        mask[(size_t)(rb0 + ri*16 + r)*2048 + j0 + js*16 + fr]
            = raw[ri][js][r] > 6.0f ? 1 : 0;
}

// ---------------------------------------------------------------------------
// Kernel 6: final masked renorm (in place on sim half of out).
// ---------------------------------------------------------------------------
__global__ __launch_bounds__(256,4) void k_final(
    float* __restrict__ out, const unsigned char* __restrict__ mask)
{
  int row  = blockIdx.x*4 + (threadIdx.x>>6);
  int lane = threadIdx.x & 63;
  float* sr = out + 4194304ull + (size_t)row*2048;
  const unsigned char* mr = mask + (size_t)row*2048;
  float v[32];
  float sum2 = 0.0f;
  #pragma unroll
  for (int c=0;c<32;c++){
    float e = __expf(sr[c*64 + lane]);
    v[c] = (mr[c*64 + lane] != 0) ? e : 0.0f;
    sum2 += v[c];
  }
  #pragma unroll
  for (int m=1;m<64;m<<=1) sum2 += __shfl_xor(sum2, m);
  float inv = 1.0f / sum2;
  #pragma unroll
  for (int c=0;c<32;c++) sr[c*64 + lane] = v[c]*inv;
}

// ---------------------------------------------------------------------------
extern "C" void kernel_launch(void* const* d_in, const int* in_sizes, int n_in,
                              void* d_out, int out_size, void* d_ws, size_t ws_size,
                              hipStream_t stream)
{
  const float* xcls = (const float*)d_in[0];
  const float* xreg = (const float*)d_in[1];
  const float* csc  = (const float*)d_in[2];
  const float* fsc  = (const float*)d_in[3];
  const float* Wc   = (const float*)d_in[4];
  const float* Wr   = (const float*)d_in[5];
  float* out = (float*)d_out;

  char* ws = (char*)d_ws;
  short* xbc = (short*)ws;
  short* xbr = xbc + 2097152;
  short* wbc = xbr + 2097152;           // 3145728 shorts
  short* wbr = wbc + 3145728;
  unsigned char* mask = (unsigned char*)ws;
  char* accbase       = ws + 4u*1024*1024;
  float* s_cls        = (float*)(accbase);
  float* s_reg        = (float*)(accbase + 65536);
  short* Up           = (short*)(accbase + 131072);   // 4 x 4.19MB bf16 partials
  short* qc = (short*)(ws + 41943040ull);
  short* kc = qc + 2097152;
  short* qr = kc + 2097152;
  short* kr = qr + 2097152;
  short* vn = kr + 2097152;
  short* vb = vn + 2097152;
  short* vT = vb + 2097152;

  k_cvt  <<<4608,        256, 0, stream>>>(xcls, xreg, Wc, Wr, xbc, xbr, wbc, wbr);
  k_qkv  <<<640,         256, 0, stream>>>(xbc, xbr, wbc, wbr,
                                           qc, kc, qr, kr, vn, vb, out);
  k_vT   <<<512,         256, 0, stream>>>(vb, vT);
  hipMemsetAsync(accbase, 0, 131072, stream);   // zero s_cls/s_reg only
  k_attn <<<512,         256, 0, stream>>>(qc, kc, qr, kr, vT, csc, fsc,
                                           s_cls, s_reg, Up);
  k_attn_fin <<<4096,    256, 0, stream>>>(Up, s_cls, s_reg, out);
  k_raw  <<<dim3(16,32), 256, 0, stream>>>(vn, mask);
  k_sim  <<<dim3(16,32), 256, 0, stream>>>(qc, kc, qr, kr, csc, fsc,
                                           s_cls, s_reg, out);
  k_final<<<512,         256, 0, stream>>>(out, mask);
}

// Round 19
// 241.336 us; speedup vs baseline: 1.1569x; 1.0025x over previous
//
#include <hip/hip_runtime.h>

// ---------------------------------------------------------------------------
// Attention_msa: B=1, N=2048, C=1024, H=8, d=128, SCALE=25, SIM_THRESH=0.75
// R18 base (241.9 us) + k_attn 3-phase flattening (setprio removed there).
// ---------------------------------------------------------------------------

#define NTOK 2048
#define CDIM 1024

typedef __attribute__((ext_vector_type(8))) short bf16x8;
typedef __attribute__((ext_vector_type(4))) short s16x4;
typedef __attribute__((ext_vector_type(2))) short s16x2;
typedef __attribute__((ext_vector_type(4))) float f32x4;

#define MFMA16(a,b,c) __builtin_amdgcn_mfma_f32_16x16x32_bf16((a),(b),(c),0,0,0)

__device__ __forceinline__ short f2bf(float x){
  unsigned u = __float_as_uint(x);
  u += 0x7FFFu + ((u >> 16) & 1u);           // round-to-nearest-even
  return (short)(u >> 16);
}

__device__ __forceinline__ float bf2f(short s){
  return __uint_as_float(((unsigned)(unsigned short)s) << 16);
}

__device__ __forceinline__ int cvtpk(float lo, float hi){
  int r;
  asm("v_cvt_pk_bf16_f32 %0, %1, %2" : "=v"(r) : "v"(lo), "v"(hi));
  return r;
}

__device__ __forceinline__ void atomAddF(float* p, float v){
  unsafeAtomicAdd(p, v);                     // global_atomic_add_f32
}

// async global->LDS, 16B per lane; LDS dest = uniform base + lane*16
__device__ __forceinline__ void gld16(const short* g, short* l){
  __builtin_amdgcn_global_load_lds(
      (const __attribute__((address_space(1))) unsigned int*)g,
      (__attribute__((address_space(3))) unsigned int*)l, 16, 0, 0);
}

// ---------------------------------------------------------------------------
// Kernel 0: f32 -> bf16 conversion of GEMM inputs (one pass).
// ---------------------------------------------------------------------------
__global__ __launch_bounds__(256,8) void k_cvt(
    const float* __restrict__ xc, const float* __restrict__ xr,
    const float* __restrict__ Wc, const float* __restrict__ Wr,
    short* __restrict__ xbc, short* __restrict__ xbr,
    short* __restrict__ wbc, short* __restrict__ wbr)
{
  int idx = blockIdx.x*256 + threadIdx.x;    // 0..1179647
  const float* src; short* dst; int off;
  if      (idx <  262144){ src = xc; dst = xbc; off = idx; }
  else if (idx <  524288){ src = xr; dst = xbr; off = idx - 262144; }
  else if (idx <  917504){ src = Wc; dst = wbc; off = idx - 524288; }
  else                   { src = Wr; dst = wbr; off = idx - 917504; }
  float4 a = *(const float4*)(src + (size_t)off*8);
  float4 b = *(const float4*)(src + (size_t)off*8 + 4);
  bf16x8 o = { f2bf(a.x), f2bf(a.y), f2bf(a.z), f2bf(a.w),
               f2bf(b.x), f2bf(b.y), f2bf(b.z), f2bf(b.w) };
  *(bf16x8*)(dst + (size_t)off*8) = o;
}

// ---------------------------------------------------------------------------
// Kernel 1: QKV GEMM + FUSED per-head L2 norm.
// ---------------------------------------------------------------------------
__global__ __launch_bounds__(256,3) void k_qkv(
    const short* __restrict__ xbc, const short* __restrict__ xbr,
    const short* __restrict__ wbc, const short* __restrict__ wbr,
    short* __restrict__ qc, short* __restrict__ kc,
    short* __restrict__ qr, short* __restrict__ kr,
    short* __restrict__ vn, short* __restrict__ vb,
    float* __restrict__ out)
{
  const int tid = threadIdx.x;
  const int l   = tid & 63;
  const int w   = tid >> 6;
  const int fr  = l & 15;
  const int g   = l >> 4;
  const int fk8 = g * 8;

  const int L     = blockIdx.x;
  const int xcd   = L & 7;
  const int slot  = L >> 3;              // 0..79
  const int panel = xcd*5 + (slot >> 4); // 0..39
  const int mb    = slot & 15;
  const int m0    = mb * 128;
  const int o0    = panel * 128;

  const short* Xb; const short* Wb; int wrow;
  if (o0 < 3072){ Xb = xbc; Wb = wbc; wrow = o0; }
  else          { Xb = xbr; Wb = wbr; wrow = o0 - 3072; }

  __shared__ __align__(16) short Ab[2][8][64][8];   // 16KB (double)
  __shared__ __align__(16) short Bb[2][8][64][8];   // 16KB (double)
  __shared__ float nbuf[128][2];

  const int wr = w >> 1;
  const int wc = w & 1;

#define QSTAGE(DB, KN) do {                                                  \
    _Pragma("unroll")                                                        \
    for (int it=0; it<2; ++it){                                              \
      int f = it*4 + w;                                                      \
      gld16(Xb + (size_t)(m0  + f*16 + fr)*CDIM + (KN) + fk8,                \
            &Ab[DB][f][0][0]);                                               \
      gld16(Wb + (size_t)(wrow + f*16 + fr)*CDIM + (KN) + fk8,               \
            &Bb[DB][f][0][0]);                                               \
    }                                                                        \
  } while(0)

  f32x4 acc[4][4] = {};

  QSTAGE(0, 0);
  __syncthreads();

  for (int kt = 0; kt < 32; ++kt){
    const int db = kt & 1;
    if (kt < 31){ if (db) QSTAGE(0, (kt+1)*32); else QSTAGE(1, (kt+1)*32); }
    bf16x8 af[4], bfr[4];
    #pragma unroll
    for (int ai=0;ai<4;ai++) af[ai]  = *(const bf16x8*)&Ab[db][wr*4+ai][l][0];
    #pragma unroll
    for (int bj=0;bj<4;bj++) bfr[bj] = *(const bf16x8*)&Bb[db][wc*4+bj][l][0];
    #pragma unroll
    for (int ai=0;ai<4;ai++)
      #pragma unroll
      for (int bj=0;bj<4;bj++)
        acc[ai][bj] = MFMA16(af[ai], bfr[bj], acc[ai][bj]);
    __syncthreads();
  }
#undef QSTAGE

  const int chunk = o0 >> 10;
  const int hh    = (o0 >> 7) & 7;

  float rn[4][4];
  #pragma unroll
  for (int ai=0;ai<4;ai++)
    #pragma unroll
    for (int r=0;r<4;r++){
      float ss = 0.f;
      #pragma unroll
      for (int bj=0;bj<4;bj++) ss += acc[ai][bj][r]*acc[ai][bj][r];
      ss += __shfl_xor(ss, 1); ss += __shfl_xor(ss, 2);
      ss += __shfl_xor(ss, 4); ss += __shfl_xor(ss, 8);
      if (fr == 0) nbuf[wr*64 + ai*16 + g*4 + r][wc] = ss;
      rn[ai][r] = ss;
    }
  __syncthreads();
  #pragma unroll
  for (int ai=0;ai<4;ai++)
    #pragma unroll
    for (int r=0;r<4;r++){
      int row = wr*64 + ai*16 + g*4 + r;
      rn[ai][r] = rsqrtf(nbuf[row][0] + nbuf[row][1]);
    }

  #pragma unroll
  for (int ai=0;ai<4;ai++)
    #pragma unroll
    for (int r=0;r<4;r++){
      int n   = m0 + wr*64 + ai*16 + g*4 + r;
      size_t base = ((size_t)hh*NTOK + n)*128;
      #pragma unroll
      for (int bj=0;bj<4;bj++){
        int col = wc*64 + bj*16 + fr;
        float val = acc[ai][bj][r];
        short nv  = f2bf(val * rn[ai][r]);
        switch(chunk){
          case 0: qc[base+col] = nv; break;
          case 1: kc[base+col] = nv; break;
          case 3: qr[base+col] = nv; break;
          case 4: kr[base+col] = nv; break;
          default:
            vn[base+col] = nv;
            vb[base+col] = f2bf(val);
            out[(size_t)n*2048 + 1024 + hh*128 + col] = val;
            break;
        }
      }
    }
}

// ---------------------------------------------------------------------------
// Kernel 3: transpose raw v (bf16) [h][n][d] -> vT [h][d][n]
// ---------------------------------------------------------------------------
__global__ __launch_bounds__(256,4) void k_vT(
    const short* __restrict__ vb, short* __restrict__ vT)
{
  int b = blockIdx.x;
  int h  = b >> 6;
  int nt = (b >> 1) & 31;
  int dt = b & 1;
  __shared__ short t[64][72];
  int tid = threadIdx.x;
  int r  = tid >> 2;
  int c0 = (tid & 3) << 4;
  #pragma unroll
  for (int u=0;u<2;u++){
    bf16x8 val = *(const bf16x8*)&vb[((size_t)h*NTOK + nt*64 + r)*128 + dt*64 + c0 + u*8];
    #pragma unroll
    for (int e=0;e<8;e++) t[r][c0+u*8+e] = val[e];
  }
  __syncthreads();
  #pragma unroll
  for (int u=0;u<2;u++){
    bf16x8 o;
    #pragma unroll
    for (int e=0;e<8;e++) o[e] = t[c0+u*8+e][r];
    *(bf16x8*)&vT[((size_t)h*128 + dt*64 + r)*NTOK + nt*64 + c0 + u*8] = o;
  }
}

// ---------------------------------------------------------------------------
// Kernel 4: attention partial pass. R18 memory structure; inner iteration
// flattened into 3 phases (all QK MFMAs -> all exp/pack VALU -> gathers+PV)
// so the scheduler gets 16-deep independent MFMA issue and cross-pipe
// overlap; setprio removed (T5 null-to-negative on lockstep kernels, m190).
// ---------------------------------------------------------------------------
#define JLEN 1024

__global__ __launch_bounds__(256,2) void k_attn(
    const short* __restrict__ qc, const short* __restrict__ kc,
    const short* __restrict__ qr, const short* __restrict__ kr,
    const short* __restrict__ vT,
    const float* __restrict__ csc, const float* __restrict__ fsc,
    float* __restrict__ s_cls, float* __restrict__ s_reg,
    short* __restrict__ Up)
{
  const int tid = threadIdx.x;
  const int l   = tid & 63;
  const int w   = tid >> 6;
  const int L    = blockIdx.x;            // 0..511
  const int xcd  = L & 7;
  const int slot = L >> 3;                // 0..63
  const int hs   = ((slot >> 5) << 3) | xcd;   // 0..15
  const int h    = hs >> 1;
  const int s    = hs & 1;
  const int rem  = slot & 31;
  const int js   = rem >> 4;
  const int ib   = rem & 15;

  const int iw  = ib * 128 + w * 32;
  const int fr  = l & 15;
  const int g   = l >> 4;
  const int fk8 = g * 8;
  const size_t hN = (size_t)h * NTOK;
  const size_t hD = (size_t)h * 128;

  const short* Qp = s ? qr : qc;
  const short* Kp = s ? kr : kc;
  const float* sc = s ? fsc : csc;
  float* ssum     = s ? s_reg : s_cls;
  short* Ub       = Up + (size_t)(js*2 + s) * 2097152;

  __shared__ __align__(16) short Kbuf[2][4][4][64][8];   // 32KB (double)
  __shared__ __align__(16) short Vbuf[2][8][2][64][8];   // 32KB (double)

  const int t8 = w * 8;

#define STAGE(DB, JN) do {                                                   \
    _Pragma("unroll")                                                        \
    for (int q8=0; q8<8; ++q8){                                              \
      int t = t8 + q8;                                                       \
      if (t < 16){                                                           \
        int jf = t >> 2, kk = t & 3;                                         \
        gld16(Kp + (hN + (JN) + jf*16 + fr)*128 + kk*32 + fk8,               \
              &Kbuf[DB][jf][kk][0][0]);                                      \
      } else {                                                               \
        int u = t - 16, df = u >> 1, ks = u & 1;                             \
        gld16(vT + (hD + df*16 + fr)*2048 + (JN) + ks*32 + fk8,              \
              &Vbuf[DB][df][ks][0][0]);                                      \
      }                                                                      \
    }                                                                        \
  } while(0)

  bf16x8 bq[2][4];
  #pragma unroll
  for (int i2=0;i2<2;i2++)
    #pragma unroll
    for (int kk=0;kk<4;kk++)
      bq[i2][kk] = *(const bf16x8*)&Qp[(hN + iw + i2*16 + fr)*128 + kk*32 + fk8];

  float sci[2];
  sci[0] = sc[iw + fr] - 0.1f;
  sci[1] = sc[iw + 16 + fr] - 0.1f;

  f32x4 U[2][8] = {};
  float p[2] = {0.f, 0.f};

  const int srcA = ((((g<<1)    & 3) << 4) + fr) << 2;
  const int srcB = ((((g<<1 | 1)& 3) << 4) + fr) << 2;
  const bool ghi = g >= 2;
  const int jbase = js * JLEN;

  STAGE(0, jbase);
  __syncthreads();

  for (int jt = 0; jt < 16; ++jt){
    const int db = jt & 1;
    const int j0 = jbase + jt*64;
    if (jt < 15){ if (db) STAGE(0, j0 + 64); else STAGE(1, j0 + 64); }

    // ---- Phase 1: all QK^T MFMAs (independent across jf) ----
    f32x4 S0[4], S1[4];
    #pragma unroll
    for (int jf=0; jf<4; ++jf){
      S0[jf] = (f32x4){0.f,0.f,0.f,0.f};
      S1[jf] = (f32x4){0.f,0.f,0.f,0.f};
      #pragma unroll
      for (int kk=0; kk<4; ++kk){
        bf16x8 kb = *(const bf16x8*)&Kbuf[db][jf][kk][l][0];
        S0[jf] = MFMA16(kb, bq[0][kk], S0[jf]);   // S^T: row=j, col=i
        S1[jf] = MFMA16(kb, bq[1][kk], S1[jf]);
      }
    }
    // ---- Phase 2: exp + pack (VALU) ----
    int cpk[2][4][2];             // [i2][jf][pair]
    #pragma unroll
    for (int jf=0; jf<4; ++jf){
      float4 sjv = *(const float4*)&sc[j0 + jf*16 + 4*g];
      float e0[4], e1[4];
      #pragma unroll
      for (int r=0;r<4;r++){
        float sj = (&sjv.x)[r];
        float sj25 = 25.0f * sj;
        e0[r] = (sj > sci[0]) ? __expf(S0[jf][r]*sj25) : 1.0f;
        e1[r] = (sj > sci[1]) ? __expf(S1[jf][r]*sj25) : 1.0f;
        p[0] += e0[r]; p[1] += e1[r];
      }
      cpk[0][jf][0] = cvtpk(e0[0], e0[1]);
      cpk[0][jf][1] = cvtpk(e0[2], e0[3]);
      cpk[1][jf][0] = cvtpk(e1[0], e1[1]);
      cpk[1][jf][1] = cvtpk(e1[2], e1[3]);
    }
    // ---- Phase 3: gathers + PV ----
    #pragma unroll
    for (int ks=0; ks<2; ++ks){
      bf16x8 ea[2];
      #pragma unroll
      for (int i2=0;i2<2;i2++){
        int a0 = __builtin_amdgcn_ds_bpermute(srcA, cpk[i2][ks*2  ][0]);
        int a1 = __builtin_amdgcn_ds_bpermute(srcA, cpk[i2][ks*2  ][1]);
        int a2 = __builtin_amdgcn_ds_bpermute(srcA, cpk[i2][ks*2+1][0]);
        int a3 = __builtin_amdgcn_ds_bpermute(srcA, cpk[i2][ks*2+1][1]);
        int b0 = __builtin_amdgcn_ds_bpermute(srcB, cpk[i2][ks*2  ][0]);
        int b1 = __builtin_amdgcn_ds_bpermute(srcB, cpk[i2][ks*2  ][1]);
        int b2 = __builtin_amdgcn_ds_bpermute(srcB, cpk[i2][ks*2+1][0]);
        int b3 = __builtin_amdgcn_ds_bpermute(srcB, cpk[i2][ks*2+1][1]);
        int wd[4];
        wd[0] = ghi ? a2 : a0;  wd[1] = ghi ? a3 : a1;
        wd[2] = ghi ? b2 : b0;  wd[3] = ghi ? b3 : b1;
        ea[i2] = *(bf16x8*)wd;
      }
      #pragma unroll
      for (int df=0; df<8; ++df){
        bf16x8 bv = *(const bf16x8*)&Vbuf[db][df][ks][l][0];
        U[0][df] = MFMA16(ea[0], bv, U[0][df]);
        U[1][df] = MFMA16(ea[1], bv, U[1][df]);
      }
    }
    __syncthreads();
  }
#undef STAGE

  #pragma unroll
  for (int i2=0;i2<2;i2++){
    p[i2] += __shfl_xor(p[i2], 16);
    p[i2] += __shfl_xor(p[i2], 32);
  }
  if (l < 16){
    atomAddF(&ssum[hN + iw + l],      p[0]);
    atomAddF(&ssum[hN + iw + 16 + l], p[1]);
  }
  #pragma unroll
  for (int i2=0;i2<2;i2++)
    #pragma unroll
    for (int df=0;df<8;df++)
      #pragma unroll
      for (int r=0;r<4;r++)
        Ub[(hN + iw + i2*16 + g*4 + r)*128 + df*16 + fr] = f2bf(U[i2][df][r]);
}

// ---------------------------------------------------------------------------
// Kernel 4b: combine bf16 partials -> out = 0.5*(sum Uc/sc + sum Ur/sr)
// ---------------------------------------------------------------------------
__global__ __launch_bounds__(256,8) void k_attn_fin(
    const short* __restrict__ Up,
    const float* __restrict__ s_cls, const float* __restrict__ s_reg,
    float* __restrict__ out)
{
  int task = blockIdx.x*4 + (threadIdx.x>>6);   // h*2048 + row
  int lane = threadIdx.x & 63;
  int h = task >> 11;
  int row = task & 2047;
  size_t b = (size_t)task*128 + lane*2;
  float cx=0.f, cy=0.f, rx=0.f, ry=0.f;
  #pragma unroll
  for (int js=0; js<2; ++js){
    s16x2 c = *(const s16x2*)(Up + (size_t)(js*2+0)*2097152 + b);
    s16x2 r = *(const s16x2*)(Up + (size_t)(js*2+1)*2097152 + b);
    cx += bf2f(c[0]); cy += bf2f(c[1]);
    rx += bf2f(r[0]); ry += bf2f(r[1]);
  }
  float isc = 0.5f/s_cls[task];
  float isr = 0.5f/s_reg[task];
  float2 o = { cx*isc + rx*isr, cy*isc + ry*isr };
  *(float2*)&out[(size_t)row*2048 + h*128 + lane*2] = o;
}

// ---------------------------------------------------------------------------
// Kernel 5: sim_attn (128i x 64j, grid (16,32), gld16 staging).
// ---------------------------------------------------------------------------
__global__ __launch_bounds__(256,2) void k_sim(
    const short* __restrict__ qc, const short* __restrict__ kc,
    const short* __restrict__ qr, const short* __restrict__ kr,
    const float* __restrict__ csc, const float* __restrict__ fsc,
    const float* __restrict__ s_cls, const float* __restrict__ s_reg,
    float* __restrict__ out)
{
  const int tid  = threadIdx.x;
  const int lane = tid & 63;
  const int w    = tid >> 6;
  const int i0w  = blockIdx.x * 128 + w * 32;
  const int j0   = blockIdx.y * 64;
  const int fr   = lane & 15;
  const int fk   = (lane >> 4) * 8;

  __shared__ __align__(16) short Bsh[2][16][64][8];   // 32 KiB

  float sjc[4], sjf[4];
  #pragma unroll
  for (int js=0;js<4;js++){ sjc[js]=csc[j0+js*16+fr]; sjf[js]=fsc[j0+js*16+fr]; }
  int rowb[2]; float sci[2][4], sfi[2][4];
  #pragma unroll
  for (int ri=0;ri<2;ri++){
    rowb[ri] = i0w + ri*16 + ((lane>>4)<<2);
    #pragma unroll
    for (int r=0;r<4;r++){ sci[ri][r]=csc[rowb[ri]+r]; sfi[ri][r]=fsc[rowb[ri]+r]; }
  }

  f32x4 sim[2][4] = {};

  for (int h=0; h<8; ++h){
    const size_t hb = (size_t)h * NTOK;
    __syncthreads();                    // prior head's LDS reads complete
    #pragma unroll
    for (int it=0; it<8; ++it){
      int t   = it*4 + w;               // 0..31
      int str = t >> 4;                 // 0=kc 1=kr
      int f   = t & 15;                 // frag index
      const short* gp = str ? kr : kc;
      int r = (f >> 2)*16 + fr;
      int c = (f & 3)*32 + fk;
      gld16(gp + (hb + j0 + r)*128 + c, &Bsh[str][f][0][0]);
    }
    bf16x8 aq[2][4], ar[2][4];
    #pragma unroll
    for (int ri=0;ri<2;ri++)
      #pragma unroll
      for (int kk=0;kk<4;kk++){
        aq[ri][kk] = *(const bf16x8*)&qc[(hb + i0w + ri*16 + fr)*128 + kk*32 + fk];
        ar[ri][kk] = *(const bf16x8*)&qr[(hb + i0w + ri*16 + fr)*128 + kk*32 + fk];
      }
    float iscl[2][4], isrl[2][4];
    #pragma unroll
    for (int ri=0;ri<2;ri++)
      #pragma unroll
      for (int r=0;r<4;r++){
        iscl[ri][r] = 1.0f/s_cls[hb + rowb[ri] + r];
        isrl[ri][r] = 1.0f/s_reg[hb + rowb[ri] + r];
      }
    __syncthreads();                    // drains gld16s
    #pragma unroll
    for (int js=0; js<4; ++js){
      bf16x8 bc[4], br[4];
      #pragma unroll
      for (int kk=0;kk<4;kk++){
        bc[kk] = *(const bf16x8*)&Bsh[0][js*4+kk][lane][0];
        br[kk] = *(const bf16x8*)&Bsh[1][js*4+kk][lane][0];
      }
      #pragma unroll
      for (int ri=0;ri<2;ri++){
        f32x4 Sc = {}; f32x4 Sr = {};
        __builtin_amdgcn_s_setprio(1);
        #pragma unroll
        for (int kk=0;kk<4;kk++){
          Sc = MFMA16(aq[ri][kk], bc[kk], Sc);
          Sr = MFMA16(ar[ri][kk], br[kk], Sr);
        }
        __builtin_amdgcn_s_setprio(0);
        #pragma unroll
        for (int r=0;r<4;r++){
          float ec = (sjc[js] > sci[ri][r]-0.1f) ? __expf(Sc[r]*(25.0f*sjc[js])) : 1.0f;
          float er = (sjf[js] > sfi[ri][r]-0.1f) ? __expf(Sr[r]*(25.0f*sjf[js])) : 1.0f;
          sim[ri][js][r] += ec*iscl[ri][r] + er*isrl[ri][r];
        }
      }
    }
  }
  #pragma unroll
  for (int ri=0;ri<2;ri++)
    #pragma unroll
    for (int js=0;js<4;js++)
      #pragma unroll
      for (int r=0;r<4;r++)
        out[4194304ull + (size_t)(rowb[ri]+r)*2048 + j0 + js*16 + fr]
            = sim[ri][js][r] * 0.0625f;
}

// ---------------------------------------------------------------------------
// Kernel 5b: raw = Vn . Vn^T over full C=1024; mask = raw>6.  gld16 staging.
// ---------------------------------------------------------------------------
__global__ __launch_bounds__(256,4) void k_raw(
    const short* __restrict__ vn, unsigned char* __restrict__ mask)
{
  const int tid  = threadIdx.x;
  const int lane = tid & 63;
  const int w    = tid >> 6;
  const int i0w  = blockIdx.x * 128 + w * 32;
  const int j0   = blockIdx.y * 64;
  const int fr   = lane & 15;
  const int fk   = (lane >> 4) * 8;

  __shared__ __align__(16) short Bsh[16][64][8];   // 16 KiB

  f32x4 raw[2][4] = {};

  for (int cc=0; cc<8; ++cc){
    const size_t hb = (size_t)cc * NTOK;
    __syncthreads();
    #pragma unroll
    for (int it=0; it<4; ++it){
      int f = it*4 + w;                 // 0..15
      int r = (f >> 2)*16 + fr;
      int c = (f & 3)*32 + fk;
      gld16(vn + (hb + j0 + r)*128 + c, &Bsh[f][0][0]);
    }
    bf16x8 av[2][4];
    #pragma unroll
    for (int ri=0;ri<2;ri++)
      #pragma unroll
      for (int kk=0;kk<4;kk++)
        av[ri][kk] = *(const bf16x8*)&vn[(hb + i0w + ri*16 + fr)*128 + kk*32 + fk];
    __syncthreads();
    #pragma unroll
    for (int js=0; js<4; ++js){
      bf16x8 bv[4];
      #pragma unroll
      for (int kk=0;kk<4;kk++) bv[kk] = *(const bf16x8*)&Bsh[js*4+kk][lane][0];
      #pragma unroll
      for (int ri=0;ri<2;ri++)
        #pragma unroll
        for (int kk=0;kk<4;kk++)
          raw[ri][js] = MFMA16(av[ri][kk], bv[kk], raw[ri][js]);
    }
  }
  const int rb0 = i0w + ((lane>>4)<<2);
  #pragma unroll
  for (int ri=0;ri<2;ri++)
    #pragma unroll
    for (int js=0;js<4;js++)
      #pragma unroll
      for (int r=0;r<4;r++)
        mask[(size_t)(rb0 + ri*16 + r)*2048 + j0 + js*16 + fr]
            = raw[ri][js][r] > 6.0f ? 1 : 0;
}

// ---------------------------------------------------------------------------
// Kernel 6: final masked renorm (in place on sim half of out).
// ---------------------------------------------------------------------------
__global__ __launch_bounds__(256,4) void k_final(
    float* __restrict__ out, const unsigned char* __restrict__ mask)
{
  int row  = blockIdx.x*4 + (threadIdx.x>>6);
  int lane = threadIdx.x & 63;
  float* sr = out + 4194304ull + (size_t)row*2048;
  const unsigned char* mr = mask + (size_t)row*2048;
  float v[32];
  float sum2 = 0.0f;
  #pragma unroll
  for (int c=0;c<32;c++){
    float e = __expf(sr[c*64 + lane]);
    v[c] = (mr[c*64 + lane] != 0) ? e : 0.0f;
    sum2 += v[c];
  }
  #pragma unroll
  for (int m=1;m<64;m<<=1) sum2 += __shfl_xor(sum2, m);
  float inv = 1.0f / sum2;
  #pragma unroll
  for (int c=0;c<32;c++) sr[c*64 + lane] = v[c]*inv;
}

// ---------------------------------------------------------------------------
extern "C" void kernel_launch(void* const* d_in, const int* in_sizes, int n_in,
                              void* d_out, int out_size, void* d_ws, size_t ws_size,
                              hipStream_t stream)
{
  const float* xcls = (const float*)d_in[0];
  const float* xreg = (const float*)d_in[1];
  const float* csc  = (const float*)d_in[2];
  const float* fsc  = (const float*)d_in[3];
  const float* Wc   = (const float*)d_in[4];
  const float* Wr   = (const float*)d_in[5];
  float* out = (float*)d_out;

  char* ws = (char*)d_ws;
  short* xbc = (short*)ws;
  short* xbr = xbc + 2097152;
  short* wbc = xbr + 2097152;           // 3145728 shorts
  short* wbr = wbc + 3145728;
  unsigned char* mask = (unsigned char*)ws;
  char* accbase       = ws + 4u*1024*1024;
  float* s_cls        = (float*)(accbase);
  float* s_reg        = (float*)(accbase + 65536);
  short* Up           = (short*)(accbase + 131072);   // 4 x 4.19MB bf16 partials
  short* qc = (short*)(ws + 41943040ull);
  short* kc = qc + 2097152;
  short* qr = kc + 2097152;
  short* kr = qr + 2097152;
  short* vn = kr + 2097152;
  short* vb = vn + 2097152;
  short* vT = vb + 2097152;

  k_cvt  <<<4608,        256, 0, stream>>>(xcls, xreg, Wc, Wr, xbc, xbr, wbc, wbr);
  k_qkv  <<<640,         256, 0, stream>>>(xbc, xbr, wbc, wbr,
                                           qc, kc, qr, kr, vn, vb, out);
  k_vT   <<<512,         256, 0, stream>>>(vb, vT);
  hipMemsetAsync(accbase, 0, 131072, stream);   // zero s_cls/s_reg only
  k_attn <<<512,         256, 0, stream>>>(qc, kc, qr, kr, vT, csc, fsc,
                                           s_cls, s_reg, Up);
  k_attn_fin <<<4096,    256, 0, stream>>>(Up, s_cls, s_reg, out);
  k_raw  <<<dim3(16,32), 256, 0, stream>>>(vn, mask);
  k_sim  <<<dim3(16,32), 256, 0, stream>>>(qc, kc, qr, kr, csc, fsc,
                                           s_cls, s_reg, out);
  k_final<<<512,         256, 0, stream>>>(out, mask);
}